// Round 3
// baseline (300.858 us; speedup 1.0000x reference)
//
#include <hip/hip_runtime.h>

#define D 256

typedef unsigned short ushort_t;
typedef unsigned int uint_t;
typedef __attribute__((ext_vector_type(8))) short short8;
typedef __attribute__((ext_vector_type(4))) float floatx4;

static __device__ __forceinline__ ushort_t f2bf(float f) {
    union { float f; uint_t u; } c; c.f = f;
    uint_t r = (c.u + 0x7FFFu + ((c.u >> 16) & 1u)) >> 16;   // RN-even
    return (ushort_t)r;
}
static __device__ __forceinline__ float bf2f(ushort_t b) {
    union { uint_t u; float f; } c; c.u = ((uint_t)b) << 16;
    return c.f;
}

// async global->LDS DMA, 16B per lane, dest = uniform base + lane*16
static __device__ __forceinline__ void async16(const void* g, void* l) {
    __builtin_amdgcn_global_load_lds(
        (const __attribute__((address_space(1))) void*)g,
        (__attribute__((address_space(3))) void*)l, 16, 0, 0);
}

// ---------------------------------------------------------------------------
// Fused prep, 3 grid sections:
//  [0,degB):      rank[e] = atomicAdd(&deg[col[e]],1)  (histogram + edge rank)
//  [degB,+cvtB):  x -> bf16 (xh)
//  rest:          BT[j][k] j-major: k<256 Wself[k][j] | k<512 Wsrc | k<768 Wdst
// ---------------------------------------------------------------------------
__global__ void prep_kernel(const int* __restrict__ col, int* __restrict__ deg,
                            int* __restrict__ rank,
                            const float* __restrict__ x, ushort_t* __restrict__ xh,
                            const float* __restrict__ Wself, const float* __restrict__ Wsrc,
                            const float* __restrict__ Wdst, ushort_t* __restrict__ BT,
                            int E, int total8, int degB, int cvtB) {
    int b = blockIdx.x;
    if (b < degB) {
        int e = b * 256 + threadIdx.x;
        if (e < E) rank[e] = atomicAdd(&deg[col[e]], 1);
    } else if (b < degB + cvtB) {
        int i = (b - degB) * 256 + threadIdx.x;
        if (i >= total8) return;
        float4 a = ((const float4*)x)[i * 2];
        float4 bb = ((const float4*)x)[i * 2 + 1];
        uint4 o;
        o.x = f2bf(a.x) | ((uint_t)f2bf(a.y) << 16);
        o.y = f2bf(a.z) | ((uint_t)f2bf(a.w) << 16);
        o.z = f2bf(bb.x) | ((uint_t)f2bf(bb.y) << 16);
        o.w = f2bf(bb.z) | ((uint_t)f2bf(bb.w) << 16);
        ((uint4*)xh)[i] = o;
    } else {
        int id = (b - degB - cvtB) * 256 + threadIdx.x;   // j*768+k
        if (id >= 256 * 768) return;
        int j = id / 768, k = id % 768;
        float v;
        if (k < 256)      v = Wself[(size_t)k * 256 + j];
        else if (k < 512) v = Wsrc [(size_t)(k - 256) * 256 + j];
        else              v = Wdst [(size_t)(k - 512) * 256 + j];
        BT[id] = f2bf(v);
    }
}

// ---------------------------------------------------------------------------
// Scan phase A: per-block (1024 elems) local exclusive scan into off,
// block totals into partials. 256 threads x int4.
// ---------------------------------------------------------------------------
__global__ __launch_bounds__(256) void scanA(const int* __restrict__ deg,
                                             int* __restrict__ off,
                                             int* __restrict__ partials, int n4) {
    __shared__ int wtot[4];
    const int tid = threadIdx.x, lane = tid & 63, wid = tid >> 6;
    int i4 = blockIdx.x * 256 + tid;
    int4 v = (i4 < n4) ? ((const int4*)deg)[i4] : make_int4(0, 0, 0, 0);
    int s = v.x + v.y + v.z + v.w;
    int incl = s;
    #pragma unroll
    for (int st = 1; st < 64; st <<= 1) {
        int t = __shfl_up(incl, st, 64);
        if (lane >= st) incl += t;
    }
    if (lane == 63) wtot[wid] = incl;
    __syncthreads();
    int wbase = 0;
    #pragma unroll
    for (int w = 0; w < 4; ++w) if (w < wid) wbase += wtot[w];
    int excl = incl - s + wbase;
    if (i4 < n4) {
        int4 o;
        o.x = excl; o.y = o.x + v.x; o.z = o.y + v.y; o.w = o.z + v.z;
        ((int4*)off)[i4] = o;
    }
    if (tid == 0) partials[blockIdx.x] = wtot[0] + wtot[1] + wtot[2] + wtot[3];
}

// ---------------------------------------------------------------------------
// Scan phase C: add exclusive block base (sum of earlier partials, <=64 blocks).
// ---------------------------------------------------------------------------
__global__ __launch_bounds__(256) void scanC(int* __restrict__ off,
                                             const int* __restrict__ partials, int n4) {
    __shared__ int base_s;
    const int tid = threadIdx.x;
    if (tid < 64) {
        int v = (tid < blockIdx.x) ? partials[tid] : 0;
        #pragma unroll
        for (int st = 32; st; st >>= 1) v += __shfl_down(v, st, 64);
        if (tid == 0) base_s = v;
    }
    __syncthreads();
    int base = base_s;
    int i4 = blockIdx.x * 256 + tid;
    if (i4 < n4) {
        int4 o = ((int4*)off)[i4];
        o.x += base; o.y += base; o.z += base; o.w += base;
        ((int4*)off)[i4] = o;
    }
}

// ---------------------------------------------------------------------------
// Atomic-free bucket fill using precomputed ranks.
// ---------------------------------------------------------------------------
__global__ void fill_kernel(const int* __restrict__ row, const int* __restrict__ col,
                            const int* __restrict__ rank, const int* __restrict__ off,
                            int* __restrict__ bucket, int E) {
    int e = blockIdx.x * blockDim.x + threadIdx.x;
    if (e >= E) return;
    bucket[off[col[e]] + rank[e]] = row[e];
}

// ---------------------------------------------------------------------------
// Per-node gather-sum over bf16 rows, fp32 accum, bf16 out. One wave/node,
// lane = 4 consecutive bf16 (8B). 4-wide unroll for MLP.
// ---------------------------------------------------------------------------
__global__ __launch_bounds__(256) void segsum_kernel(const ushort_t* __restrict__ xh,
                                                     const int* __restrict__ off,
                                                     const int* __restrict__ deg,
                                                     const int* __restrict__ bucket,
                                                     ushort_t* __restrict__ Gh, int N) {
    int node = blockIdx.x * 4 + (threadIdx.x >> 6);
    int lane = threadIdx.x & 63;
    if (node >= N) return;
    int start = off[node];
    int cnt = deg[node];
    float a0 = 0.f, a1 = 0.f, a2 = 0.f, a3 = 0.f;
    int i = 0;
    for (; i + 4 <= cnt; i += 4) {
        int r0 = bucket[start + i];
        int r1 = bucket[start + i + 1];
        int r2 = bucket[start + i + 2];
        int r3 = bucket[start + i + 3];
        ushort4 v0 = ((const ushort4*)(xh + (size_t)r0 * D))[lane];
        ushort4 v1 = ((const ushort4*)(xh + (size_t)r1 * D))[lane];
        ushort4 v2 = ((const ushort4*)(xh + (size_t)r2 * D))[lane];
        ushort4 v3 = ((const ushort4*)(xh + (size_t)r3 * D))[lane];
        a0 += (bf2f(v0.x) + bf2f(v1.x)) + (bf2f(v2.x) + bf2f(v3.x));
        a1 += (bf2f(v0.y) + bf2f(v1.y)) + (bf2f(v2.y) + bf2f(v3.y));
        a2 += (bf2f(v0.z) + bf2f(v1.z)) + (bf2f(v2.z) + bf2f(v3.z));
        a3 += (bf2f(v0.w) + bf2f(v1.w)) + (bf2f(v2.w) + bf2f(v3.w));
    }
    for (; i < cnt; ++i) {
        int r0 = bucket[start + i];
        ushort4 v0 = ((const ushort4*)(xh + (size_t)r0 * D))[lane];
        a0 += bf2f(v0.x); a1 += bf2f(v0.y); a2 += bf2f(v0.z); a3 += bf2f(v0.w);
    }
    ushort4 o;
    o.x = f2bf(a0); o.y = f2bf(a1); o.z = f2bf(a2); o.w = f2bf(a3);
    ((ushort4*)(Gh + (size_t)node * D))[lane] = o;
}

// ---------------------------------------------------------------------------
// bf16 MFMA GEMM v3: single accumulator over K=768, high occupancy.
//   out[i][j] = x@Wself + G@Wsrc - (deg o x)@Wdst + bself + deg*(bsrc-bdst)
// A-panels (kt = 0..23, BK=32):
//   kt 0..7 : xh           kt 8..15: Gh          kt 16..23: xh scaled by -deg
// The -deg row-scale is applied IN-REGISTER to the A fragment (lane's A-row
// is mg*16 + (lane&15)), so no extra HBM stream and no weight-sign change.
// Tile: BM=64 x BN=128, 4 waves (2x2), per-wave 32x64 -> acc = 2x4 floatx4
// = 32 VGPRs. launch_bounds(256,4): 128-reg cap, est. ~100 used -> 4 waves/
// SIMD, LDS 24 KB -> 4 blocks/CU (16 waves, 50% occ) vs old 2 blocks/8 waves.
// Round-2 lesson: 2-phase dbuf is neutral at low occupancy -- the fix is TLP.
// Round-1 lesson: never set launch_bounds above what the acc regs allow.
// ---------------------------------------------------------------------------
__global__ __launch_bounds__(256, 4) void mfma_gemm(
    const ushort_t* __restrict__ xh, const ushort_t* __restrict__ Gh,
    const ushort_t* __restrict__ BT, const int* __restrict__ deg,
    const float* __restrict__ bsrc, const float* __restrict__ bdst,
    const float* __restrict__ bself, float* __restrict__ out, int N)
{
    __shared__ ushort_t As[2][4][64][8];   //  8 KB (64 rows x 32 k per stage)
    __shared__ ushort_t Bs[2][8][64][8];   // 16 KB (128 cols x 32 k per stage)

    const int tid = threadIdx.x;
    const int lane = tid & 63, wave = tid >> 6;
    const int quad = lane >> 4, l15 = lane & 15;
    const int wr = wave >> 1, wc = wave & 1;         // 2x2 wave grid
    const int mbase = blockIdx.x * 64, nbase = blockIdx.y * 128;

    // staging: this wave stages A group `wave`, B groups 2*wave, 2*wave+1
    int ar = mbase + wave * 16 + l15; if (ar >= N) ar = N - 1;
    const size_t aoff = (size_t)ar * 256 + quad * 8;
    const ushort_t* bp0 = BT + (size_t)(nbase + (wave * 2) * 16 + l15) * 768 + quad * 8;
    const ushort_t* bp1 = BT + (size_t)(nbase + (wave * 2 + 1) * 16 + l15) * 768 + quad * 8;

    // -deg for the rows this wave's A fragments hold (row = mg*16 + l15)
    float negdeg[2];
    #pragma unroll
    for (int im = 0; im < 2; ++im) {
        int r = mbase + (wr * 2 + im) * 16 + l15; if (r >= N) r = N - 1;
        negdeg[im] = -(float)deg[r];
    }

    floatx4 acc[2][4] = {};

    // ---- prologue: stage kt=0 (xh panel) into buffer 0 ----
    async16(xh + aoff, &As[0][wave][0][0]);
    async16(bp0, &Bs[0][wave * 2][0][0]);
    async16(bp1, &Bs[0][wave * 2 + 1][0][0]);
    asm volatile("s_waitcnt vmcnt(0)" ::: "memory");
    __builtin_amdgcn_s_barrier();

    #pragma unroll
    for (int kt = 0; kt < 24; ++kt) {
        const int cur = kt & 1, nxt = cur ^ 1;

        // ---- issue next stage's DMA first (overlaps with MFMA below) ----
        if (kt < 23) {
            const int k1 = kt + 1;
            const ushort_t* Ap = (k1 < 8) ? xh : (k1 < 16 ? Gh : xh);
            const int ka = (k1 & 7) * 32;          // k-col within A panel
            async16(Ap + aoff + ka, &As[nxt][wave][0][0]);
            async16(bp0 + k1 * 32, &Bs[nxt][wave * 2][0][0]);
            async16(bp1 + k1 * 32, &Bs[nxt][wave * 2 + 1][0][0]);
        }

        // ---- compute current stage ----
        short8 af[2], bfr[4];
        #pragma unroll
        for (int im = 0; im < 2; ++im)
            af[im] = *(const short8*)(&As[cur][wr * 2 + im][lane][0]);
        #pragma unroll
        for (int in = 0; in < 4; ++in)
            bfr[in] = *(const short8*)(&Bs[cur][wc * 4 + in][lane][0]);
        asm volatile("s_waitcnt lgkmcnt(0)" ::: "memory");

        if (kt >= 16) {
            // third panel: scale A fragment rows by -deg (fold of (deg o x)@Wdst)
            #pragma unroll
            for (int im = 0; im < 2; ++im) {
                short8 t = af[im];
                #pragma unroll
                for (int j = 0; j < 8; ++j) {
                    float f = bf2f((ushort_t)t[j]) * negdeg[im];
                    t[j] = (short)f2bf(f);
                }
                af[im] = t;
            }
        }

        #pragma unroll
        for (int im = 0; im < 2; ++im)
            #pragma unroll
            for (int in = 0; in < 4; ++in)
                acc[im][in] = __builtin_amdgcn_mfma_f32_16x16x32_bf16(
                    af[im], bfr[in], acc[im][in], 0, 0, 0);

        // ---- single per-kt drain; prefetch above had the MFMA to hide under
        if (kt < 23) {
            asm volatile("s_waitcnt vmcnt(0)" ::: "memory");
            __builtin_amdgcn_s_barrier();
        }
    }

    // deg for the 8 rows this thread writes (bias term only now)
    float degv[2][4];
    #pragma unroll
    for (int im = 0; im < 2; ++im)
        #pragma unroll
        for (int r = 0; r < 4; ++r) {
            int gm = mbase + wr * 32 + im * 16 + quad * 4 + r;
            degv[im][r] = (gm < N) ? (float)deg[gm] : 0.f;
        }

    // C/D layout: col = lane&15, row = quad*4 + reg
    #pragma unroll
    for (int in = 0; in < 4; ++in) {
        int gn = nbase + wc * 64 + in * 16 + l15;
        float bs = bself[gn];
        float db = bsrc[gn] - bdst[gn];
        #pragma unroll
        for (int im = 0; im < 2; ++im) {
            #pragma unroll
            for (int r = 0; r < 4; ++r) {
                int gm = mbase + wr * 32 + im * 16 + quad * 4 + r;
                if (gm < N) {
                    out[(size_t)gm * 256 + gn] =
                        acc[im][in][r] + bs + degv[im][r] * db;
                }
            }
        }
    }
}

extern "C" void kernel_launch(void* const* d_in, const int* in_sizes, int n_in,
                              void* d_out, int out_size, void* d_ws, size_t ws_size,
                              hipStream_t stream) {
    const float* x     = (const float*)d_in[0];
    const int*   eidx  = (const int*)d_in[1];
    const float* Wsrc  = (const float*)d_in[2];
    const float* bsrc  = (const float*)d_in[3];
    const float* Wdst  = (const float*)d_in[4];
    const float* bdst  = (const float*)d_in[5];
    const float* Wself = (const float*)d_in[6];
    const float* bself = (const float*)d_in[7];
    float* out = (float*)d_out;

    const int N = in_sizes[0] / D;       // 50000
    const int E = in_sizes[1] / 2;       // 800000
    const int* row = eidx;
    const int* col = eidx + E;

    // ws layout: xh | Gh | BT | deg | off | partials | bucket
    // rank[] (E ints) is ALIASED onto Gh: dead before segsum writes Gh.
    char* p = (char*)d_ws;
    ushort_t* xh  = (ushort_t*)p;        p += (size_t)N * D * sizeof(ushort_t);
    ushort_t* Gh  = (ushort_t*)p;        int* rank = (int*)p;
                                         p += (size_t)N * D * sizeof(ushort_t);
    ushort_t* BT  = (ushort_t*)p;        p += (size_t)768 * 256 * sizeof(ushort_t);
    int* deg      = (int*)p;             p += (size_t)N * sizeof(int);
    int* off      = (int*)p;             p += (size_t)N * sizeof(int);
    int* partials = (int*)p;             p += 64 * sizeof(int);
    int* bucket   = (int*)p;

    hipMemsetAsync(deg, 0, (size_t)N * sizeof(int), stream);

    const int total8 = N * D / 8;                 // 1,600,000
    const int degB = (E + 255) / 256;             // 3125
    const int cvtB = (total8 + 255) / 256;        // 6250
    const int btB  = (256 * 768 + 255) / 256;     // 768
    prep_kernel<<<degB + cvtB + btB, 256, 0, stream>>>(col, deg, rank, x, xh,
                                                       Wself, Wsrc, Wdst, BT,
                                                       E, total8, degB, cvtB);
    const int n4 = N / 4;                         // 12500
    const int nblk = (n4 + 255) / 256;            // 49 (<= 64 required by scanC)
    scanA<<<nblk, 256, 0, stream>>>(deg, off, partials, n4);
    scanC<<<nblk, 256, 0, stream>>>(off, partials, n4);
    fill_kernel<<<(E + 255) / 256, 256, 0, stream>>>(row, col, rank, off, bucket, E);
    segsum_kernel<<<(N + 3) / 4, 256, 0, stream>>>(xh, off, deg, bucket, Gh, N);

    dim3 grid((N + 63) / 64, 2);
    mfma_gemm<<<grid, 256, 0, stream>>>(xh, Gh, BT, deg, bsrc, bdst, bself, out, N);
}

// Round 4
// 284.297 us; speedup vs baseline: 1.0583x; 1.0583x over previous
//
#include <hip/hip_runtime.h>

#define D 256

typedef unsigned short ushort_t;
typedef unsigned int uint_t;
typedef __attribute__((ext_vector_type(8))) short short8;
typedef __attribute__((ext_vector_type(4))) float floatx4;

static __device__ __forceinline__ ushort_t f2bf(float f) {
    union { float f; uint_t u; } c; c.f = f;
    uint_t r = (c.u + 0x7FFFu + ((c.u >> 16) & 1u)) >> 16;   // RN-even
    return (ushort_t)r;
}
static __device__ __forceinline__ float bf2f(ushort_t b) {
    union { uint_t u; float f; } c; c.u = ((uint_t)b) << 16;
    return c.f;
}

// async global->LDS DMA, 16B per lane, dest = uniform base + lane*16
static __device__ __forceinline__ void async16(const void* g, void* l) {
    __builtin_amdgcn_global_load_lds(
        (const __attribute__((address_space(1))) void*)g,
        (__attribute__((address_space(3))) void*)l, 16, 0, 0);
}

// counted vmcnt wait (constant-folds after full unroll; guide T4)
static __device__ __forceinline__ void wait_vmcnt_rt(int n) {
    switch (n) {
        case 0:  asm volatile("s_waitcnt vmcnt(0)"  ::: "memory"); break;
        case 4:  asm volatile("s_waitcnt vmcnt(4)"  ::: "memory"); break;
        case 8:  asm volatile("s_waitcnt vmcnt(8)"  ::: "memory"); break;
        case 10: asm volatile("s_waitcnt vmcnt(10)" ::: "memory"); break;
        default: asm volatile("s_waitcnt vmcnt(12)" ::: "memory"); break;
    }
}

// ---------------------------------------------------------------------------
// Fused prep, 3 grid sections:
//  [0,degB):      rank[e] = atomicAdd(&deg[col[e]],1)  (histogram + edge rank)
//  [degB,+cvtB):  x -> bf16 (xh)
//  rest:          BT[j][k] j-major: k<256 Wself[k][j] | k<512 Wsrc | k<768 Wdst
// ---------------------------------------------------------------------------
__global__ void prep_kernel(const int* __restrict__ col, int* __restrict__ deg,
                            int* __restrict__ rank,
                            const float* __restrict__ x, ushort_t* __restrict__ xh,
                            const float* __restrict__ Wself, const float* __restrict__ Wsrc,
                            const float* __restrict__ Wdst, ushort_t* __restrict__ BT,
                            int E, int total8, int degB, int cvtB) {
    int b = blockIdx.x;
    if (b < degB) {
        int e = b * 256 + threadIdx.x;
        if (e < E) rank[e] = atomicAdd(&deg[col[e]], 1);
    } else if (b < degB + cvtB) {
        int i = (b - degB) * 256 + threadIdx.x;
        if (i >= total8) return;
        float4 a = ((const float4*)x)[i * 2];
        float4 bb = ((const float4*)x)[i * 2 + 1];
        uint4 o;
        o.x = f2bf(a.x) | ((uint_t)f2bf(a.y) << 16);
        o.y = f2bf(a.z) | ((uint_t)f2bf(a.w) << 16);
        o.z = f2bf(bb.x) | ((uint_t)f2bf(bb.y) << 16);
        o.w = f2bf(bb.z) | ((uint_t)f2bf(bb.w) << 16);
        ((uint4*)xh)[i] = o;
    } else {
        int id = (b - degB - cvtB) * 256 + threadIdx.x;   // j*768+k
        if (id >= 256 * 768) return;
        int j = id / 768, k = id % 768;
        float v;
        if (k < 256)      v = Wself[(size_t)k * 256 + j];
        else if (k < 512) v = Wsrc [(size_t)(k - 256) * 256 + j];
        else              v = Wdst [(size_t)(k - 512) * 256 + j];
        BT[id] = f2bf(v);
    }
}

// ---------------------------------------------------------------------------
// Scan phase A: per-block (1024 elems) local exclusive scan into off,
// block totals into partials. 256 threads x int4.
// ---------------------------------------------------------------------------
__global__ __launch_bounds__(256) void scanA(const int* __restrict__ deg,
                                             int* __restrict__ off,
                                             int* __restrict__ partials, int n4) {
    __shared__ int wtot[4];
    const int tid = threadIdx.x, lane = tid & 63, wid = tid >> 6;
    int i4 = blockIdx.x * 256 + tid;
    int4 v = (i4 < n4) ? ((const int4*)deg)[i4] : make_int4(0, 0, 0, 0);
    int s = v.x + v.y + v.z + v.w;
    int incl = s;
    #pragma unroll
    for (int st = 1; st < 64; st <<= 1) {
        int t = __shfl_up(incl, st, 64);
        if (lane >= st) incl += t;
    }
    if (lane == 63) wtot[wid] = incl;
    __syncthreads();
    int wbase = 0;
    #pragma unroll
    for (int w = 0; w < 4; ++w) if (w < wid) wbase += wtot[w];
    int excl = incl - s + wbase;
    if (i4 < n4) {
        int4 o;
        o.x = excl; o.y = o.x + v.x; o.z = o.y + v.y; o.w = o.z + v.z;
        ((int4*)off)[i4] = o;
    }
    if (tid == 0) partials[blockIdx.x] = wtot[0] + wtot[1] + wtot[2] + wtot[3];
}

// ---------------------------------------------------------------------------
// Scan phase C: add exclusive block base (sum of earlier partials, <=64 blocks).
// ---------------------------------------------------------------------------
__global__ __launch_bounds__(256) void scanC(int* __restrict__ off,
                                             const int* __restrict__ partials, int n4) {
    __shared__ int base_s;
    const int tid = threadIdx.x;
    if (tid < 64) {
        int v = (tid < blockIdx.x) ? partials[tid] : 0;
        #pragma unroll
        for (int st = 32; st; st >>= 1) v += __shfl_down(v, st, 64);
        if (tid == 0) base_s = v;
    }
    __syncthreads();
    int base = base_s;
    int i4 = blockIdx.x * 256 + tid;
    if (i4 < n4) {
        int4 o = ((int4*)off)[i4];
        o.x += base; o.y += base; o.z += base; o.w += base;
        ((int4*)off)[i4] = o;
    }
}

// ---------------------------------------------------------------------------
// Atomic-free bucket fill using precomputed ranks.
// ---------------------------------------------------------------------------
__global__ void fill_kernel(const int* __restrict__ row, const int* __restrict__ col,
                            const int* __restrict__ rank, const int* __restrict__ off,
                            int* __restrict__ bucket, int E) {
    int e = blockIdx.x * blockDim.x + threadIdx.x;
    if (e >= E) return;
    bucket[off[col[e]] + rank[e]] = row[e];
}

// ---------------------------------------------------------------------------
// Per-node gather-sum over bf16 rows, fp32 accum, bf16 out. One wave/node,
// lane = 4 consecutive bf16 (8B). 4-wide unroll for MLP.
// ---------------------------------------------------------------------------
__global__ __launch_bounds__(256) void segsum_kernel(const ushort_t* __restrict__ xh,
                                                     const int* __restrict__ off,
                                                     const int* __restrict__ deg,
                                                     const int* __restrict__ bucket,
                                                     ushort_t* __restrict__ Gh, int N) {
    int node = blockIdx.x * 4 + (threadIdx.x >> 6);
    int lane = threadIdx.x & 63;
    if (node >= N) return;
    int start = off[node];
    int cnt = deg[node];
    float a0 = 0.f, a1 = 0.f, a2 = 0.f, a3 = 0.f;
    int i = 0;
    for (; i + 4 <= cnt; i += 4) {
        int r0 = bucket[start + i];
        int r1 = bucket[start + i + 1];
        int r2 = bucket[start + i + 2];
        int r3 = bucket[start + i + 3];
        ushort4 v0 = ((const ushort4*)(xh + (size_t)r0 * D))[lane];
        ushort4 v1 = ((const ushort4*)(xh + (size_t)r1 * D))[lane];
        ushort4 v2 = ((const ushort4*)(xh + (size_t)r2 * D))[lane];
        ushort4 v3 = ((const ushort4*)(xh + (size_t)r3 * D))[lane];
        a0 += (bf2f(v0.x) + bf2f(v1.x)) + (bf2f(v2.x) + bf2f(v3.x));
        a1 += (bf2f(v0.y) + bf2f(v1.y)) + (bf2f(v2.y) + bf2f(v3.y));
        a2 += (bf2f(v0.z) + bf2f(v1.z)) + (bf2f(v2.z) + bf2f(v3.z));
        a3 += (bf2f(v0.w) + bf2f(v1.w)) + (bf2f(v2.w) + bf2f(v3.w));
    }
    for (; i < cnt; ++i) {
        int r0 = bucket[start + i];
        ushort4 v0 = ((const ushort4*)(xh + (size_t)r0 * D))[lane];
        a0 += bf2f(v0.x); a1 += bf2f(v0.y); a2 += bf2f(v0.z); a3 += bf2f(v0.w);
    }
    ushort4 o;
    o.x = f2bf(a0); o.y = f2bf(a1); o.z = f2bf(a2); o.w = f2bf(a3);
    ((ushort4*)(Gh + (size_t)node * D))[lane] = o;
}

// ---------------------------------------------------------------------------
// bf16 MFMA GEMM v4: 128x128 dual-accumulator tile (round-0 geometry) with a
// 3-buffer ring + COUNTED vmcnt pipeline (guide T4 -- never drain to 0 in the
// main loop). Per stage kt:
//   issue DMA for stage kt+2 into buf[(kt+2)%3]           (stays in flight)
//   s_waitcnt vmcnt(L(kt+1)+L(kt+2))  -> stage kt's loads complete; the
//                                        8-12 newer loads remain outstanding
//   s_barrier; ds_read buf[kt%3]; MFMA; s_barrier
// Issue-to-wait distance = 2 full stages, vs round-2's issue->drain0 in the
// SAME stage (which exposed ~600-900 cy of L2/HBM latency per stage -- the
// measured ~1600 cy/stage wall vs ~300 cy work).
// L(s) = loads/wave/stage = 6 (s<8: A,B,D) or 4 (8<=s<16: A,B).
// LDS 3 x 24 KB = 72 KB -> 2 blocks/CU. launch_bounds(256,2): round-1 lesson,
// the 128-reg accumulator pair needs the 256-reg budget.
//   kt 0..7 : A=xh tile; acc1 += A@Wself-tile, acc2 += A@Wdst-tile (A reused)
//   kt 8..15: A=Gh tile; acc1 += A@Wsrc-tile
//   out = acc1 - deg*acc2 + bself + deg*(bsrc-bdst)
// ---------------------------------------------------------------------------
__global__ __launch_bounds__(256, 2) void mfma_gemm(
    const ushort_t* __restrict__ xh, const ushort_t* __restrict__ Gh,
    const ushort_t* __restrict__ BT, const int* __restrict__ deg,
    const float* __restrict__ bsrc, const float* __restrict__ bdst,
    const float* __restrict__ bself, float* __restrict__ out, int N)
{
    __shared__ ushort_t As[3][8][64][8];   // 24 KB
    __shared__ ushort_t Bs[3][8][64][8];   // 24 KB
    __shared__ ushort_t Ds[3][8][64][8];   // 24 KB (Wdst tiles, stages < 8)

    const int tid = threadIdx.x;
    const int lane = tid & 63, wave = tid >> 6;
    const int quad = lane >> 4, l15 = lane & 15;
    const int mg = (wave >> 1) * 4, ng = (wave & 1) * 4;   // fragment group bases
    const int mbase = blockIdx.x * 128, nbase = blockIdx.y * 128;

    // this wave stages groups ga0, ga1 of each tile
    const int ga0 = wave * 2, ga1 = ga0 + 1;
    int ar0 = mbase + ga0 * 16 + l15; if (ar0 >= N) ar0 = N - 1;
    int ar1 = mbase + ga1 * 16 + l15; if (ar1 >= N) ar1 = N - 1;
    const size_t aoff0 = (size_t)ar0 * 256 + quad * 8;
    const size_t aoff1 = (size_t)ar1 * 256 + quad * 8;
    const ushort_t* bp0 = BT + (size_t)(nbase + ga0 * 16 + l15) * 768 + quad * 8;
    const ushort_t* bp1 = BT + (size_t)(nbase + ga1 * 16 + l15) * 768 + quad * 8;

    floatx4 acc1[4][4] = {};
    floatx4 acc2[4][4] = {};

    // stage s into ring buffer b (6 loads for s<8, 4 loads for s>=8)
    auto stage = [&](int s, int b) {
        const ushort_t* Ap = (s < 8) ? xh : Gh;
        const int ka = (s & 7) * 32;
        const int kb = s * 32;
        async16(Ap + aoff0 + ka, &As[b][ga0][0][0]);
        async16(Ap + aoff1 + ka, &As[b][ga1][0][0]);
        async16(bp0 + kb, &Bs[b][ga0][0][0]);
        async16(bp1 + kb, &Bs[b][ga1][0][0]);
        if (s < 8) {
            async16(bp0 + 512 + kb, &Ds[b][ga0][0][0]);
            async16(bp1 + 512 + kb, &Ds[b][ga1][0][0]);
        }
    };

    // ---- prologue: stage 0 and 1; NO drain (first counted wait is in-loop)
    stage(0, 0);
    stage(1, 1);

    #pragma unroll
    for (int kt = 0; kt < 16; ++kt) {
        const int cur = kt % 3;

        // issue stage kt+2 (its buffer was released by the barrier at the
        // end of iteration kt-1)
        if (kt < 14) stage(kt + 2, (kt + 2) % 3);

        // counted wait: stage kt's loads done; stages kt+1, kt+2 stay in flight
        const int l1 = (kt + 1 < 8) ? 6 : ((kt + 1 < 16) ? 4 : 0);
        const int l2 = (kt + 2 < 8) ? 6 : ((kt + 2 < 16) ? 4 : 0);
        wait_vmcnt_rt(l1 + l2);
        __builtin_amdgcn_s_barrier();

        // ---- compute current stage ----
        short8 af[4], bfr[4];
        #pragma unroll
        for (int im = 0; im < 4; ++im)
            af[im] = *(const short8*)(&As[cur][mg + im][lane][0]);
        #pragma unroll
        for (int in = 0; in < 4; ++in)
            bfr[in] = *(const short8*)(&Bs[cur][ng + in][lane][0]);
        #pragma unroll
        for (int im = 0; im < 4; ++im)
            #pragma unroll
            for (int in = 0; in < 4; ++in)
                acc1[im][in] = __builtin_amdgcn_mfma_f32_16x16x32_bf16(
                    af[im], bfr[in], acc1[im][in], 0, 0, 0);
        if (kt < 8) {
            short8 df[4];
            #pragma unroll
            for (int in = 0; in < 4; ++in)
                df[in] = *(const short8*)(&Ds[cur][ng + in][lane][0]);
            #pragma unroll
            for (int im = 0; im < 4; ++im)
                #pragma unroll
                for (int in = 0; in < 4; ++in)
                    acc2[im][in] = __builtin_amdgcn_mfma_f32_16x16x32_bf16(
                        af[im], df[in], acc2[im][in], 0, 0, 0);
        }

        // release buf[cur] for the DMA issued at the top of iteration kt+1
        // (which targets (kt+3)%3 == cur)
        if (kt < 15) __builtin_amdgcn_s_barrier();
    }

    // hoist deg for the 16 rows this thread writes
    float degv[4][4];
    #pragma unroll
    for (int im = 0; im < 4; ++im)
        #pragma unroll
        for (int r = 0; r < 4; ++r) {
            int gm = mbase + (wave >> 1) * 64 + im * 16 + quad * 4 + r;
            degv[im][r] = (gm < N) ? (float)deg[gm] : 0.f;
        }

    // C/D layout: col = lane&15, row = quad*4 + reg
    #pragma unroll
    for (int in = 0; in < 4; ++in) {
        int gn = nbase + (wave & 1) * 64 + in * 16 + l15;
        float bs = bself[gn];
        float db = bsrc[gn] - bdst[gn];
        #pragma unroll
        for (int im = 0; im < 4; ++im) {
            #pragma unroll
            for (int r = 0; r < 4; ++r) {
                int gm = mbase + (wave >> 1) * 64 + im * 16 + quad * 4 + r;
                if (gm < N) {
                    float d = degv[im][r];
                    out[(size_t)gm * 256 + gn] =
                        acc1[im][in][r] - d * acc2[im][in][r] + bs + d * db;
                }
            }
        }
    }
}

extern "C" void kernel_launch(void* const* d_in, const int* in_sizes, int n_in,
                              void* d_out, int out_size, void* d_ws, size_t ws_size,
                              hipStream_t stream) {
    const float* x     = (const float*)d_in[0];
    const int*   eidx  = (const int*)d_in[1];
    const float* Wsrc  = (const float*)d_in[2];
    const float* bsrc  = (const float*)d_in[3];
    const float* Wdst  = (const float*)d_in[4];
    const float* bdst  = (const float*)d_in[5];
    const float* Wself = (const float*)d_in[6];
    const float* bself = (const float*)d_in[7];
    float* out = (float*)d_out;

    const int N = in_sizes[0] / D;       // 50000
    const int E = in_sizes[1] / 2;       // 800000
    const int* row = eidx;
    const int* col = eidx + E;

    // ws layout: xh | Gh | BT | deg | off | partials | bucket
    // rank[] (E ints) is ALIASED onto Gh: dead before segsum writes Gh.
    char* p = (char*)d_ws;
    ushort_t* xh  = (ushort_t*)p;        p += (size_t)N * D * sizeof(ushort_t);
    ushort_t* Gh  = (ushort_t*)p;        int* rank = (int*)p;
                                         p += (size_t)N * D * sizeof(ushort_t);
    ushort_t* BT  = (ushort_t*)p;        p += (size_t)768 * 256 * sizeof(ushort_t);
    int* deg      = (int*)p;             p += (size_t)N * sizeof(int);
    int* off      = (int*)p;             p += (size_t)N * sizeof(int);
    int* partials = (int*)p;             p += 64 * sizeof(int);
    int* bucket   = (int*)p;

    hipMemsetAsync(deg, 0, (size_t)N * sizeof(int), stream);

    const int total8 = N * D / 8;                 // 1,600,000
    const int degB = (E + 255) / 256;             // 3125
    const int cvtB = (total8 + 255) / 256;        // 6250
    const int btB  = (256 * 768 + 255) / 256;     // 768
    prep_kernel<<<degB + cvtB + btB, 256, 0, stream>>>(col, deg, rank, x, xh,
                                                       Wself, Wsrc, Wdst, BT,
                                                       E, total8, degB, cvtB);
    const int n4 = N / 4;                         // 12500
    const int nblk = (n4 + 255) / 256;            // 49 (<= 64 required by scanC)
    scanA<<<nblk, 256, 0, stream>>>(deg, off, partials, n4);
    scanC<<<nblk, 256, 0, stream>>>(off, partials, n4);
    fill_kernel<<<(E + 255) / 256, 256, 0, stream>>>(row, col, rank, off, bucket, E);
    segsum_kernel<<<(N + 3) / 4, 256, 0, stream>>>(xh, off, deg, bucket, Gh, N);

    dim3 grid((N + 127) / 128, 2);
    mfma_gemm<<<grid, 256, 0, stream>>>(xh, Gh, BT, deg, bsrc, bdst, bself, out, N);
}

// Round 5
// 279.227 us; speedup vs baseline: 1.0775x; 1.0182x over previous
//
#include <hip/hip_runtime.h>

#define D 256

typedef unsigned short ushort_t;
typedef unsigned int uint_t;
typedef __attribute__((ext_vector_type(8))) short short8;
typedef __attribute__((ext_vector_type(4))) float floatx4;

static __device__ __forceinline__ ushort_t f2bf(float f) {
    union { float f; uint_t u; } c; c.f = f;
    uint_t r = (c.u + 0x7FFFu + ((c.u >> 16) & 1u)) >> 16;   // RN-even
    return (ushort_t)r;
}
static __device__ __forceinline__ float bf2f(ushort_t b) {
    union { uint_t u; float f; } c; c.u = ((uint_t)b) << 16;
    return c.f;
}

// async global->LDS DMA, 16B per lane, dest = uniform base + lane*16
static __device__ __forceinline__ void async16(const void* g, void* l) {
    __builtin_amdgcn_global_load_lds(
        (const __attribute__((address_space(1))) void*)g,
        (__attribute__((address_space(3))) void*)l, 16, 0, 0);
}

// ---------------------------------------------------------------------------
// Fused prep, 3 grid sections:
//  [0,degB):      rank[e] = atomicAdd(&deg[col[e]],1)  (histogram + edge rank)
//  [degB,+cvtB):  x -> bf16 (xh)
//  rest:          BT[j][k] j-major: k<256 Wself[k][j] | k<512 Wsrc | k<768 Wdst
// ---------------------------------------------------------------------------
__global__ void prep_kernel(const int* __restrict__ col, int* __restrict__ deg,
                            int* __restrict__ rank,
                            const float* __restrict__ x, ushort_t* __restrict__ xh,
                            const float* __restrict__ Wself, const float* __restrict__ Wsrc,
                            const float* __restrict__ Wdst, ushort_t* __restrict__ BT,
                            int E, int total8, int degB, int cvtB) {
    int b = blockIdx.x;
    if (b < degB) {
        int e = b * 256 + threadIdx.x;
        if (e < E) rank[e] = atomicAdd(&deg[col[e]], 1);
    } else if (b < degB + cvtB) {
        int i = (b - degB) * 256 + threadIdx.x;
        if (i >= total8) return;
        float4 a = ((const float4*)x)[i * 2];
        float4 bb = ((const float4*)x)[i * 2 + 1];
        uint4 o;
        o.x = f2bf(a.x) | ((uint_t)f2bf(a.y) << 16);
        o.y = f2bf(a.z) | ((uint_t)f2bf(a.w) << 16);
        o.z = f2bf(bb.x) | ((uint_t)f2bf(bb.y) << 16);
        o.w = f2bf(bb.z) | ((uint_t)f2bf(bb.w) << 16);
        ((uint4*)xh)[i] = o;
    } else {
        int id = (b - degB - cvtB) * 256 + threadIdx.x;   // j*768+k
        if (id >= 256 * 768) return;
        int j = id / 768, k = id % 768;
        float v;
        if (k < 256)      v = Wself[(size_t)k * 256 + j];
        else if (k < 512) v = Wsrc [(size_t)(k - 256) * 256 + j];
        else              v = Wdst [(size_t)(k - 512) * 256 + j];
        BT[id] = f2bf(v);
    }
}

// ---------------------------------------------------------------------------
// Scan phase A: per-block (1024 elems) local exclusive scan into off,
// block totals into partials. 256 threads x int4.
// ---------------------------------------------------------------------------
__global__ __launch_bounds__(256) void scanA(const int* __restrict__ deg,
                                             int* __restrict__ off,
                                             int* __restrict__ partials, int n4) {
    __shared__ int wtot[4];
    const int tid = threadIdx.x, lane = tid & 63, wid = tid >> 6;
    int i4 = blockIdx.x * 256 + tid;
    int4 v = (i4 < n4) ? ((const int4*)deg)[i4] : make_int4(0, 0, 0, 0);
    int s = v.x + v.y + v.z + v.w;
    int incl = s;
    #pragma unroll
    for (int st = 1; st < 64; st <<= 1) {
        int t = __shfl_up(incl, st, 64);
        if (lane >= st) incl += t;
    }
    if (lane == 63) wtot[wid] = incl;
    __syncthreads();
    int wbase = 0;
    #pragma unroll
    for (int w = 0; w < 4; ++w) if (w < wid) wbase += wtot[w];
    int excl = incl - s + wbase;
    if (i4 < n4) {
        int4 o;
        o.x = excl; o.y = o.x + v.x; o.z = o.y + v.y; o.w = o.z + v.z;
        ((int4*)off)[i4] = o;
    }
    if (tid == 0) partials[blockIdx.x] = wtot[0] + wtot[1] + wtot[2] + wtot[3];
}

// ---------------------------------------------------------------------------
// Scan phase C: add exclusive block base (sum of earlier partials, <=64 blocks).
// ---------------------------------------------------------------------------
__global__ __launch_bounds__(256) void scanC(int* __restrict__ off,
                                             const int* __restrict__ partials, int n4) {
    __shared__ int base_s;
    const int tid = threadIdx.x;
    if (tid < 64) {
        int v = (tid < blockIdx.x) ? partials[tid] : 0;
        #pragma unroll
        for (int st = 32; st; st >>= 1) v += __shfl_down(v, st, 64);
        if (tid == 0) base_s = v;
    }
    __syncthreads();
    int base = base_s;
    int i4 = blockIdx.x * 256 + tid;
    if (i4 < n4) {
        int4 o = ((int4*)off)[i4];
        o.x += base; o.y += base; o.z += base; o.w += base;
        ((int4*)off)[i4] = o;
    }
}

// ---------------------------------------------------------------------------
// Atomic-free bucket fill using precomputed ranks.
// ---------------------------------------------------------------------------
__global__ void fill_kernel(const int* __restrict__ row, const int* __restrict__ col,
                            const int* __restrict__ rank, const int* __restrict__ off,
                            int* __restrict__ bucket, int E) {
    int e = blockIdx.x * blockDim.x + threadIdx.x;
    if (e >= E) return;
    bucket[off[col[e]] + rank[e]] = row[e];
}

// ---------------------------------------------------------------------------
// Per-node gather-sum over bf16 rows, fp32 accum, bf16 out. One wave/node,
// lane = 4 consecutive bf16 (8B). 4-wide unroll for MLP.
// ---------------------------------------------------------------------------
__global__ __launch_bounds__(256) void segsum_kernel(const ushort_t* __restrict__ xh,
                                                     const int* __restrict__ off,
                                                     const int* __restrict__ deg,
                                                     const int* __restrict__ bucket,
                                                     ushort_t* __restrict__ Gh, int N) {
    int node = blockIdx.x * 4 + (threadIdx.x >> 6);
    int lane = threadIdx.x & 63;
    if (node >= N) return;
    int start = off[node];
    int cnt = deg[node];
    float a0 = 0.f, a1 = 0.f, a2 = 0.f, a3 = 0.f;
    int i = 0;
    for (; i + 4 <= cnt; i += 4) {
        int r0 = bucket[start + i];
        int r1 = bucket[start + i + 1];
        int r2 = bucket[start + i + 2];
        int r3 = bucket[start + i + 3];
        ushort4 v0 = ((const ushort4*)(xh + (size_t)r0 * D))[lane];
        ushort4 v1 = ((const ushort4*)(xh + (size_t)r1 * D))[lane];
        ushort4 v2 = ((const ushort4*)(xh + (size_t)r2 * D))[lane];
        ushort4 v3 = ((const ushort4*)(xh + (size_t)r3 * D))[lane];
        a0 += (bf2f(v0.x) + bf2f(v1.x)) + (bf2f(v2.x) + bf2f(v3.x));
        a1 += (bf2f(v0.y) + bf2f(v1.y)) + (bf2f(v2.y) + bf2f(v3.y));
        a2 += (bf2f(v0.z) + bf2f(v1.z)) + (bf2f(v2.z) + bf2f(v3.z));
        a3 += (bf2f(v0.w) + bf2f(v1.w)) + (bf2f(v2.w) + bf2f(v3.w));
    }
    for (; i < cnt; ++i) {
        int r0 = bucket[start + i];
        ushort4 v0 = ((const ushort4*)(xh + (size_t)r0 * D))[lane];
        a0 += bf2f(v0.x); a1 += bf2f(v0.y); a2 += bf2f(v0.z); a3 += bf2f(v0.w);
    }
    ushort4 o;
    o.x = f2bf(a0); o.y = f2bf(a1); o.z = f2bf(a2); o.w = f2bf(a3);
    ((ushort4*)(Gh + (size_t)node * D))[lane] = o;
}

// ---------------------------------------------------------------------------
// bf16 MFMA GEMM v5: geometry restructure (rounds 0/2/4 proved the schedule
// is NOT the limiter -- three sync structures timed identically at ~66 us).
//   * BM=128 x BN=256 (full output width), grid = 391 blocks <= 512 resident
//     slots -> ONE scheduling round, no 1.53-round tail (was ~30%).
//   * A (xh/Gh) loaded DIRECTLY to registers (global_load_dwordx4 per-wave,
//     out-of-order, decoupled from the barrier-coupled DMA path); read ONCE
//     from HBM -- no grid.y A re-read, no L3-retention dependence (round-3
//     lesson: L3 does not retain streamed data).
//   * Single accumulator via the round-3-verified -deg fold, applied
//     in-register with ZERO extra A traffic: per stage s<8 the A fragment
//     is MFMA'd vs the Wself chunk, then scaled by -deg and MFMA'd vs the
//     Wdst chunk. Stages 8..15: A=Gh vs Wsrc chunk.
//   * Only B goes through global_load_lds (L2-hot: BT = 393 KB), dbuf-2,
//     counted vmcnt (never 0 mid-loop).
// acc = 4x8 floatx4 = 128 VGPRs; launch_bounds(256,2) (round-1 lesson).
// LDS 64 KB -> 2 blocks/CU.
//   out = [x|G|(-deg o x)] @ [Wself|Wsrc|Wdst] + bself + deg*(bsrc-bdst)
// ---------------------------------------------------------------------------
__global__ __launch_bounds__(256, 2) void mfma_gemm(
    const ushort_t* __restrict__ xh, const ushort_t* __restrict__ Gh,
    const ushort_t* __restrict__ BT, const int* __restrict__ deg,
    const float* __restrict__ bsrc, const float* __restrict__ bdst,
    const float* __restrict__ bself, float* __restrict__ out, int N)
{
    __shared__ ushort_t Bs[2][16][64][8];   // 32 KB: Wself chunk (s<8) / Wsrc (s>=8)
    __shared__ ushort_t Bd[2][16][64][8];   // 32 KB: Wdst chunk (s<8)

    const int tid = threadIdx.x;
    const int lane = tid & 63, wave = tid >> 6;
    const int quad = lane >> 4, l15 = lane & 15;
    const int wr = wave >> 1, wc = wave & 1;      // 2x2 wave grid: 64m x 128n
    const int mbase = blockIdx.x * 128;

    // A fragment addresses + -deg row scales (row = mbase + wr*64 + im*16 + l15)
    size_t aoff[4];
    float negdeg[4];
    #pragma unroll
    for (int im = 0; im < 4; ++im) {
        int r = mbase + wr * 64 + im * 16 + l15;
        if (r >= N) r = N - 1;
        aoff[im] = (size_t)r * 256 + (size_t)(quad * 8);
        negdeg[im] = -(float)deg[r];
    }

    // B staging: this wave stages groups wave*4 .. wave*4+3 of each chunk
    const ushort_t* bpg[4];
    #pragma unroll
    for (int t = 0; t < 4; ++t)
        bpg[t] = BT + (size_t)((wave * 4 + t) * 16 + l15) * 768 + quad * 8;

    floatx4 acc[4][8] = {};
    short8 af[2][4];

    // issue stage-s B DMA into buf s&1 (8 loads for s<8, 4 for 8<=s<16)
    auto issueB = [&](int s) {
        const int b = s & 1;
        if (s < 8) {
            const int kb = s * 32;
            #pragma unroll
            for (int t = 0; t < 4; ++t)
                async16(bpg[t] + kb, &Bs[b][wave * 4 + t][0][0]);
            #pragma unroll
            for (int t = 0; t < 4; ++t)
                async16(bpg[t] + 512 + kb, &Bd[b][wave * 4 + t][0][0]);
        } else {
            const int kb = 256 + (s - 8) * 32;
            #pragma unroll
            for (int t = 0; t < 4; ++t)
                async16(bpg[t] + kb, &Bs[b][wave * 4 + t][0][0]);
        }
    };
    // plain vector loads of stage-s A fragment into af[s&1]
    auto loadA = [&](int s) {
        const ushort_t* Ap = (s < 8) ? xh : Gh;
        const int ka = (s & 7) * 32;
        #pragma unroll
        for (int im = 0; im < 4; ++im)
            af[s & 1][im] = *(const short8*)(Ap + aoff[im] + ka);
    };

    // ---- prologue: stage 0 only (1-deep; dbuf-2 permits exactly 1 ahead) ----
    issueB(0);
    loadA(0);

    #pragma unroll
    for (int s = 0; s < 16; ++s) {
        const int cur = s & 1;

        // issue stage s+1 (its buffer was released by stage s-1's trailing
        // barrier); A loads placed BEFORE the wait asm so the "memory"
        // clobber pins their issue point here.
        if (s < 15) { issueB(s + 1); loadA(s + 1); }

        // counted wait: stage s's B-DMA + A loads complete; stage s+1's
        // (L_B(s+1) + 4 ops) remain in flight. Never 0 mid-loop (T4).
        if (s < 7)        asm volatile("s_waitcnt vmcnt(12)" ::: "memory");
        else if (s < 15)  asm volatile("s_waitcnt vmcnt(8)"  ::: "memory");
        else              asm volatile("s_waitcnt vmcnt(0)"  ::: "memory");
        __builtin_amdgcn_s_barrier();

        // chunk 1: af @ Bs   (Wself for s<8, Wsrc for s>=8)
        #pragma unroll
        for (int jn = 0; jn < 8; ++jn) {
            short8 bf = *(const short8*)(&Bs[cur][wc * 8 + jn][lane][0]);
            #pragma unroll
            for (int im = 0; im < 4; ++im)
                acc[im][jn] = __builtin_amdgcn_mfma_f32_16x16x32_bf16(
                    af[cur][im], bf, acc[im][jn], 0, 0, 0);
        }
        // chunk 2 (s<8): (-deg o af) @ Bd   (Wdst fold, zero extra A traffic)
        if (s < 8) {
            short8 afd[4];
            #pragma unroll
            for (int im = 0; im < 4; ++im) {
                short8 t = af[cur][im];
                #pragma unroll
                for (int j = 0; j < 8; ++j) {
                    float f = bf2f((ushort_t)t[j]) * negdeg[im];
                    t[j] = (short)f2bf(f);
                }
                afd[im] = t;
            }
            #pragma unroll
            for (int jn = 0; jn < 8; ++jn) {
                short8 bf = *(const short8*)(&Bd[cur][wc * 8 + jn][lane][0]);
                #pragma unroll
                for (int im = 0; im < 4; ++im)
                    acc[im][jn] = __builtin_amdgcn_mfma_f32_16x16x32_bf16(
                        afd[im], bf, acc[im][jn], 0, 0, 0);
            }
        }

        // release buf[cur] for the stage-(s+2) DMA issued at top of s+1
        if (s < 15) __builtin_amdgcn_s_barrier();
    }

    // deg for the 16 rows this thread writes (bias term)
    float degv[4][4];
    #pragma unroll
    for (int im = 0; im < 4; ++im)
        #pragma unroll
        for (int r = 0; r < 4; ++r) {
            int gm = mbase + wr * 64 + im * 16 + quad * 4 + r;
            degv[im][r] = (gm < N) ? (float)deg[gm] : 0.f;
        }

    // C/D layout: col = lane&15, row = quad*4 + reg
    #pragma unroll
    for (int jn = 0; jn < 8; ++jn) {
        int gn = wc * 128 + jn * 16 + l15;
        float bs = bself[gn];
        float db = bsrc[gn] - bdst[gn];
        #pragma unroll
        for (int im = 0; im < 4; ++im) {
            #pragma unroll
            for (int r = 0; r < 4; ++r) {
                int gm = mbase + wr * 64 + im * 16 + quad * 4 + r;
                if (gm < N) {
                    out[(size_t)gm * 256 + gn] =
                        acc[im][jn][r] + bs + degv[im][r] * db;
                }
            }
        }
    }
}

extern "C" void kernel_launch(void* const* d_in, const int* in_sizes, int n_in,
                              void* d_out, int out_size, void* d_ws, size_t ws_size,
                              hipStream_t stream) {
    const float* x     = (const float*)d_in[0];
    const int*   eidx  = (const int*)d_in[1];
    const float* Wsrc  = (const float*)d_in[2];
    const float* bsrc  = (const float*)d_in[3];
    const float* Wdst  = (const float*)d_in[4];
    const float* bdst  = (const float*)d_in[5];
    const float* Wself = (const float*)d_in[6];
    const float* bself = (const float*)d_in[7];
    float* out = (float*)d_out;

    const int N = in_sizes[0] / D;       // 50000
    const int E = in_sizes[1] / 2;       // 800000
    const int* row = eidx;
    const int* col = eidx + E;

    // ws layout: xh | Gh | BT | deg | off | partials | bucket
    // rank[] (E ints) is ALIASED onto Gh: dead before segsum writes Gh.
    char* p = (char*)d_ws;
    ushort_t* xh  = (ushort_t*)p;        p += (size_t)N * D * sizeof(ushort_t);
    ushort_t* Gh  = (ushort_t*)p;        int* rank = (int*)p;
                                         p += (size_t)N * D * sizeof(ushort_t);
    ushort_t* BT  = (ushort_t*)p;        p += (size_t)768 * 256 * sizeof(ushort_t);
    int* deg      = (int*)p;             p += (size_t)N * sizeof(int);
    int* off      = (int*)p;             p += (size_t)N * sizeof(int);
    int* partials = (int*)p;             p += 64 * sizeof(int);
    int* bucket   = (int*)p;

    hipMemsetAsync(deg, 0, (size_t)N * sizeof(int), stream);

    const int total8 = N * D / 8;                 // 1,600,000
    const int degB = (E + 255) / 256;             // 3125
    const int cvtB = (total8 + 255) / 256;        // 6250
    const int btB  = (256 * 768 + 255) / 256;     // 768
    prep_kernel<<<degB + cvtB + btB, 256, 0, stream>>>(col, deg, rank, x, xh,
                                                       Wself, Wsrc, Wdst, BT,
                                                       E, total8, degB, cvtB);
    const int n4 = N / 4;                         // 12500
    const int nblk = (n4 + 255) / 256;            // 49 (<= 64 required by scanC)
    scanA<<<nblk, 256, 0, stream>>>(deg, off, partials, n4);
    scanC<<<nblk, 256, 0, stream>>>(off, partials, n4);
    fill_kernel<<<(E + 255) / 256, 256, 0, stream>>>(row, col, rank, off, bucket, E);
    segsum_kernel<<<(N + 3) / 4, 256, 0, stream>>>(xh, off, deg, bucket, Gh, N);

    mfma_gemm<<<(N + 127) / 128, 256, 0, stream>>>(xh, Gh, BT, deg,
                                                   bsrc, bdst, bself, out, N);
}